// Round 2
// baseline (159.839 us; speedup 1.0000x reference)
//
#include <hip/hip_runtime.h>
#include <math.h>

// Problem constants (match reference)
#define N_CAM 2
#define PH 96
#define PW 144
#define NPTS 200
#define VD 32
#define VH 128
#define VW 384

constexpr float MIN_DEPTH = 1.0f;
constexpr float MAX_DEPTH = 4000.0f;
constexpr float EPS_T = 1e-10f;
constexpr float VOXEL = 2.5f;

#define SEG 8                       // lanes per ray
#define PIX_PER_BLOCK (256 / SEG)   // 32
#define TOTAL_PIX (N_CAM * PH * PW) // 27648
#define RENDER_BLOCKS (TOTAL_PIX / PIX_PER_BLOCK) // 864
#define BEV_BLOCKS ((VH * VW) / 256)              // 192
#define TOTAL_BLOCKS (RENDER_BLOCKS + BEV_BLOCKS) // 1056

__device__ __forceinline__ float huber01(float diff) {
    // (sqrt(1 + diff^2/0.01) - 1) * 0.1 ; always >= 0 so |.| is a no-op
    float t = diff * 10.0f;
    return (sqrtf(fmaf(t, t, 1.0f)) - 1.0f) * 0.1f;
}

// ws[0]=color_sum ws[1]=sil_sum ws[2]=bev_sum ws[3]=block counter (zeroed by memset)
__global__ __launch_bounds__(256) void fused_kernel(
    const float* __restrict__ dens,      // [VD*VH*VW]
    const float* __restrict__ cols,      // [3*VD*VH*VW] planar
    const float* __restrict__ tsil,      // [N_CAM*PH*PW]
    const float* __restrict__ timg,      // [N_CAM*PH*PW*3]
    const float* __restrict__ focal,     // [N_CAM*2]
    const float* __restrict__ principal, // [N_CAM*2]
    const float* __restrict__ Rm,        // [N_CAM*9]
    const float* __restrict__ Tv,        // [N_CAM*3]
    float* __restrict__ ws,
    float* __restrict__ out)
{
    const int tid = threadIdx.x;

    if (blockIdx.x < RENDER_BLOCKS) {
        // ---------------- render + losses ----------------
        const int seg = tid & (SEG - 1);
        const int pix = blockIdx.x * PIX_PER_BLOCK + (tid >> 3);

        const int n   = pix / (PH * PW);
        const int rem = pix - n * (PH * PW);
        const int h   = rem / PW;
        const int w   = rem - h * PW;

        const float dx = ((float)w + 0.5f - principal[n * 2 + 0]) / focal[n * 2 + 0];
        const float dy = ((float)h + 0.5f - principal[n * 2 + 1]) / focal[n * 2 + 1];
        const float* R  = Rm + n * 9;
        const float* Tc = Tv + n * 3;
        const float dwx = R[0] * dx + R[1] * dy + R[2];
        const float dwy = R[3] * dx + R[4] * dy + R[5];
        const float dwz = R[6] * dx + R[7] * dy + R[8];
        const float ox = -(Tc[0] * R[0] + Tc[1] * R[1] + Tc[2] * R[2]);
        const float oy = -(Tc[0] * R[3] + Tc[1] * R[4] + Tc[2] * R[5]);
        const float oz = -(Tc[0] * R[6] + Tc[1] * R[7] + Tc[2] * R[8]);

        const float inv_vox = 1.0f / VOXEL;
        const float bx = (VW - 1) * 0.5f;
        const float by = (VH - 1) * 0.5f;
        const float bz = (VD - 1) * 0.5f;
        const float dstep = (MAX_DEPTH - MIN_DEPTH) / (float)(NPTS - 1);

        // Analytic ray-box clamp in grid space: g_axis(t) in (-1, DIM).
        // Outside samples contribute exactly d=0 -> A,P *= 1.0f exactly in fp32.
        float tn = MIN_DEPTH, tf = MAX_DEPTH;
        {
            const float o3[3] = {ox, oy, oz};
            const float d3[3] = {dwx, dwy, dwz};
            const float b3[3] = {bx, by, bz};
            const float m3[3] = {(float)VW, (float)VH, (float)VD};
            #pragma unroll
            for (int ax = 0; ax < 3; ++ax) {
                const float o = o3[ax], dw = d3[ax], b = b3[ax], dim = m3[ax];
                if (fabsf(dw) > 1e-12f) {
                    const float ta = ((-1.0f - b) * VOXEL - o) / dw;
                    const float tb = ((dim  - b) * VOXEL - o) / dw;
                    tn = fmaxf(tn, fminf(ta, tb));
                    tf = fminf(tf, fmaxf(ta, tb));
                } else {
                    const float g = o * inv_vox + b;
                    if (!(g > -1.0f && g < dim)) { tn = 1.0f; tf = 0.0f; }
                }
            }
        }
        int k0 = (int)ceilf((tn - MIN_DEPTH) / dstep) - 1;  // -1 margin
        int k1 = (int)floorf((tf - MIN_DEPTH) / dstep) + 2; // exclusive, +1 margin
        k0 = max(k0, 0);
        k1 = min(k1, NPTS);
        if (k1 < k0) k1 = k0;
        const int len = k1 - k0;
        const int L = (len + SEG - 1) / SEG; // contiguous chunk per lane
        const int s0 = k0 + seg * L;
        const int s1 = min(k1, s0 + L);

        float F0 = 0.f, F1 = 0.f, F2 = 0.f;
        float A = 1.0f, P = 1.0f;
        const int S = VD * VH * VW;

        for (int k = s0; k < s1; ++k) {
            const float depth = fmaf((float)k, dstep, MIN_DEPTH);
            const float gx = fmaf(fmaf(depth, dwx, ox), inv_vox, bx);
            const float gy = fmaf(fmaf(depth, dwy, oy), inv_vox, by);
            const float gz = fmaf(fmaf(depth, dwz, oz), inv_vox, bz);

            float d = 0.f, r = 0.f, g = 0.f, b = 0.f;
            if (gx > -1.f && gx < (float)VW &&
                gy > -1.f && gy < (float)VH &&
                gz > -1.f && gz < (float)VD) {
                const float x0f = floorf(gx), y0f = floorf(gy), z0f = floorf(gz);
                const float fx = gx - x0f, fy = gy - y0f, fz = gz - z0f;
                const int x0 = (int)x0f, y0 = (int)y0f, z0 = (int)z0f;
                #pragma unroll
                for (int c8 = 0; c8 < 8; ++c8) {
                    const int dxl = c8 & 1, dyl = (c8 >> 1) & 1, dzl = c8 >> 2;
                    const int xi = x0 + dxl, yi = y0 + dyl, zi = z0 + dzl;
                    if (xi < 0 || xi >= VW || yi < 0 || yi >= VH || zi < 0 || zi >= VD)
                        continue;
                    const float wt = (dxl ? fx : 1.f - fx) *
                                     (dyl ? fy : 1.f - fy) *
                                     (dzl ? fz : 1.f - fz);
                    const int flat = (zi * VH + yi) * VW + xi;
                    d = fmaf(dens[flat],         wt, d);
                    r = fmaf(cols[flat],         wt, r);
                    g = fmaf(cols[S + flat],     wt, g);
                    b = fmaf(cols[2 * S + flat], wt, b);
                }
            }
            const float wgt = d * A;
            F0 = fmaf(wgt, r, F0);
            F1 = fmaf(wgt, g, F1);
            F2 = fmaf(wgt, b, F2);
            A *= (1.0f + EPS_T - d);
            P *= (1.0f - d);
        }

        // Combine 8 contiguous segments (lanes) of this ray via shuffle scan.
        float incl = A;
        #pragma unroll
        for (int off = 1; off < SEG; off <<= 1) {
            float t = __shfl_up(incl, off, SEG);
            if (seg >= off) incl *= t;
        }
        float excl = __shfl_up(incl, 1, SEG);
        if (seg == 0) excl = 1.0f;

        float c0 = excl * F0, c1 = excl * F1, c2 = excl * F2;
        #pragma unroll
        for (int m = 1; m < SEG; m <<= 1) {
            c0 += __shfl_xor(c0, m, SEG);
            c1 += __shfl_xor(c1, m, SEG);
            c2 += __shfl_xor(c2, m, SEG);
            P  *= __shfl_xor(P, m, SEG);
        }

        float local_col = 0.f, local_sil = 0.f;
        if (seg == 0) {
            const float opac = 1.0f - P;
            local_sil = huber01(opac - tsil[pix]);
            const float* ti = timg + pix * 3;
            local_col = huber01(c0 - ti[0]) + huber01(c1 - ti[1]) + huber01(c2 - ti[2]);
        }

        #pragma unroll
        for (int m = 1; m < 64; m <<= 1) {
            local_col += __shfl_xor(local_col, m, 64);
            local_sil += __shfl_xor(local_sil, m, 64);
        }
        __shared__ float sc[4], ss[4];
        const int wave = tid >> 6;
        if ((tid & 63) == 0) { sc[wave] = local_col; ss[wave] = local_sil; }
        __syncthreads();
        if (tid == 0) {
            atomicAdd(&ws[0], sc[0] + sc[1] + sc[2] + sc[3]);
            atomicAdd(&ws[1], ss[0] + ss[1] + ss[2] + ss[3]);
        }
    } else {
        // ---------------- BEV loss ----------------
        const int t = (blockIdx.x - RENDER_BLOCKS) * 256 + tid; // [0, VH*VW)
        float m = dens[t];
        #pragma unroll
        for (int z = 1; z < VD; ++z)
            m = fmaxf(m, dens[z * (VH * VW) + t]);
        float v = fabsf(m);
        #pragma unroll
        for (int msk = 1; msk < 64; msk <<= 1)
            v += __shfl_xor(v, msk, 64);
        __shared__ float sb[4];
        const int wave = tid >> 6;
        if ((tid & 63) == 0) sb[wave] = v;
        __syncthreads();
        if (tid == 0)
            atomicAdd(&ws[2], sb[0] + sb[1] + sb[2] + sb[3]);
    }

    // ---------------- last-block finalize ----------------
    __shared__ bool is_last;
    __threadfence(); // make this block's atomics globally visible before counting
    if (tid == 0) {
        unsigned old = atomicAdd((unsigned*)&ws[3], 1u);
        is_last = (old == (unsigned)(TOTAL_BLOCKS - 1));
    }
    __syncthreads();
    if (is_last && tid == 0) {
        const float csum = atomicAdd(&ws[0], 0.0f);
        const float ssum = atomicAdd(&ws[1], 0.0f);
        const float bsum = atomicAdd(&ws[2], 0.0f);
        out[0] = csum / (float)(N_CAM * PH * PW * 3);
        out[1] = ssum / (float)(N_CAM * PH * PW);
        out[2] = bsum / (float)(VH * VW);
    }
}

extern "C" void kernel_launch(void* const* d_in, const int* in_sizes, int n_in,
                              void* d_out, int out_size, void* d_ws, size_t ws_size,
                              hipStream_t stream) {
    const float* dens      = (const float*)d_in[0];
    const float* cols      = (const float*)d_in[1];
    const float* tsil      = (const float*)d_in[2];
    const float* timg      = (const float*)d_in[3];
    const float* focal     = (const float*)d_in[4];
    const float* principal = (const float*)d_in[5];
    const float* Rm        = (const float*)d_in[6];
    const float* Tv        = (const float*)d_in[7];
    float* ws  = (float*)d_ws;
    float* out = (float*)d_out;

    hipMemsetAsync(ws, 0, 4 * sizeof(float), stream); // sums + block counter

    fused_kernel<<<TOTAL_BLOCKS, 256, 0, stream>>>(
        dens, cols, tsil, timg, focal, principal, Rm, Tv, ws, out);
}

// Round 3
// 109.334 us; speedup vs baseline: 1.4619x; 1.4619x over previous
//
#include <hip/hip_runtime.h>
#include <math.h>

// Problem constants (match reference)
#define N_CAM 2
#define PH 96
#define PW 144
#define NPTS 200
#define VD 32
#define VH 128
#define VW 384

constexpr float MIN_DEPTH = 1.0f;
constexpr float MAX_DEPTH = 4000.0f;
constexpr float EPS_T = 1e-10f;
constexpr float VOXEL = 2.5f;

#define SEG 8                       // lanes per ray
#define PIX_PER_BLOCK (256 / SEG)   // 32
#define TOTAL_PIX (N_CAM * PH * PW) // 27648
#define RENDER_BLOCKS (TOTAL_PIX / PIX_PER_BLOCK) // 864
#define BEV_BLOCKS ((VH * VW) / 256)              // 192
#define TOTAL_BLOCKS (RENDER_BLOCKS + BEV_BLOCKS) // 1056

__device__ __forceinline__ float huber01(float diff) {
    // (sqrt(1 + diff^2/0.01) - 1) * 0.1 ; always >= 0 so |.| is a no-op
    float t = diff * 10.0f;
    return (sqrtf(fmaf(t, t, 1.0f)) - 1.0f) * 0.1f;
}

// ws[0]=color_sum ws[1]=sil_sum ws[2]=bev_sum
// NOTE: no __threadfence / grid-sync here. Each block only atomicAdds into ws;
// visibility for the reader is provided by the kernel boundary (stream order).
// Round 2 post-mortem: per-block __threadfence() = L2 wb+inv on gfx950, 1056x
// -> 90us of serialization + cold L2. Never again.
__global__ __launch_bounds__(256) void work_kernel(
    const float* __restrict__ dens,      // [VD*VH*VW]
    const float* __restrict__ cols,      // [3*VD*VH*VW] planar
    const float* __restrict__ tsil,      // [N_CAM*PH*PW]
    const float* __restrict__ timg,      // [N_CAM*PH*PW*3]
    const float* __restrict__ focal,     // [N_CAM*2]
    const float* __restrict__ principal, // [N_CAM*2]
    const float* __restrict__ Rm,        // [N_CAM*9]
    const float* __restrict__ Tv,        // [N_CAM*3]
    float* __restrict__ ws)
{
    const int tid = threadIdx.x;

    if (blockIdx.x < RENDER_BLOCKS) {
        // ---------------- render + losses ----------------
        const int seg = tid & (SEG - 1);
        const int pix = blockIdx.x * PIX_PER_BLOCK + (tid >> 3);

        const int n   = pix / (PH * PW);
        const int rem = pix - n * (PH * PW);
        const int h   = rem / PW;
        const int w   = rem - h * PW;

        const float dx = ((float)w + 0.5f - principal[n * 2 + 0]) / focal[n * 2 + 0];
        const float dy = ((float)h + 0.5f - principal[n * 2 + 1]) / focal[n * 2 + 1];
        const float* R  = Rm + n * 9;
        const float* Tc = Tv + n * 3;
        const float dwx = R[0] * dx + R[1] * dy + R[2];
        const float dwy = R[3] * dx + R[4] * dy + R[5];
        const float dwz = R[6] * dx + R[7] * dy + R[8];
        const float ox = -(Tc[0] * R[0] + Tc[1] * R[1] + Tc[2] * R[2]);
        const float oy = -(Tc[0] * R[3] + Tc[1] * R[4] + Tc[2] * R[5]);
        const float oz = -(Tc[0] * R[6] + Tc[1] * R[7] + Tc[2] * R[8]);

        const float inv_vox = 1.0f / VOXEL;
        const float bx = (VW - 1) * 0.5f;
        const float by = (VH - 1) * 0.5f;
        const float bz = (VD - 1) * 0.5f;
        const float dstep = (MAX_DEPTH - MIN_DEPTH) / (float)(NPTS - 1);

        // Analytic ray-box clamp in grid space: g_axis(t) in (-1, DIM).
        // Outside samples contribute exactly d=0 -> A,P *= 1.0f exactly in fp32.
        float tn = MIN_DEPTH, tf = MAX_DEPTH;
        {
            const float o3[3] = {ox, oy, oz};
            const float d3[3] = {dwx, dwy, dwz};
            const float b3[3] = {bx, by, bz};
            const float m3[3] = {(float)VW, (float)VH, (float)VD};
            #pragma unroll
            for (int ax = 0; ax < 3; ++ax) {
                const float o = o3[ax], dw = d3[ax], b = b3[ax], dim = m3[ax];
                if (fabsf(dw) > 1e-12f) {
                    const float ta = ((-1.0f - b) * VOXEL - o) / dw;
                    const float tb = ((dim  - b) * VOXEL - o) / dw;
                    tn = fmaxf(tn, fminf(ta, tb));
                    tf = fminf(tf, fmaxf(ta, tb));
                } else {
                    const float g = o * inv_vox + b;
                    if (!(g > -1.0f && g < dim)) { tn = 1.0f; tf = 0.0f; }
                }
            }
        }
        int k0 = (int)ceilf((tn - MIN_DEPTH) / dstep) - 1;  // -1 margin
        int k1 = (int)floorf((tf - MIN_DEPTH) / dstep) + 2; // exclusive, +1 margin
        k0 = max(k0, 0);
        k1 = min(k1, NPTS);
        if (k1 < k0) k1 = k0;
        const int len = k1 - k0;
        const int L = (len + SEG - 1) / SEG; // contiguous chunk per lane
        const int s0 = k0 + seg * L;
        const int s1 = min(k1, s0 + L);

        float F0 = 0.f, F1 = 0.f, F2 = 0.f;
        float A = 1.0f, P = 1.0f;
        const int S = VD * VH * VW;

        for (int k = s0; k < s1; ++k) {
            const float depth = fmaf((float)k, dstep, MIN_DEPTH);
            const float gx = fmaf(fmaf(depth, dwx, ox), inv_vox, bx);
            const float gy = fmaf(fmaf(depth, dwy, oy), inv_vox, by);
            const float gz = fmaf(fmaf(depth, dwz, oz), inv_vox, bz);

            float d = 0.f, r = 0.f, g = 0.f, b = 0.f;
            if (gx > -1.f && gx < (float)VW &&
                gy > -1.f && gy < (float)VH &&
                gz > -1.f && gz < (float)VD) {
                const float x0f = floorf(gx), y0f = floorf(gy), z0f = floorf(gz);
                const float fx = gx - x0f, fy = gy - y0f, fz = gz - z0f;
                const int x0 = (int)x0f, y0 = (int)y0f, z0 = (int)z0f;
                #pragma unroll
                for (int c8 = 0; c8 < 8; ++c8) {
                    const int dxl = c8 & 1, dyl = (c8 >> 1) & 1, dzl = c8 >> 2;
                    const int xi = x0 + dxl, yi = y0 + dyl, zi = z0 + dzl;
                    if (xi < 0 || xi >= VW || yi < 0 || yi >= VH || zi < 0 || zi >= VD)
                        continue;
                    const float wt = (dxl ? fx : 1.f - fx) *
                                     (dyl ? fy : 1.f - fy) *
                                     (dzl ? fz : 1.f - fz);
                    const int flat = (zi * VH + yi) * VW + xi;
                    d = fmaf(dens[flat],         wt, d);
                    r = fmaf(cols[flat],         wt, r);
                    g = fmaf(cols[S + flat],     wt, g);
                    b = fmaf(cols[2 * S + flat], wt, b);
                }
            }
            const float wgt = d * A;
            F0 = fmaf(wgt, r, F0);
            F1 = fmaf(wgt, g, F1);
            F2 = fmaf(wgt, b, F2);
            A *= (1.0f + EPS_T - d);
            P *= (1.0f - d);
        }

        // Combine 8 contiguous segments (lanes) of this ray via shuffle scan.
        float incl = A;
        #pragma unroll
        for (int off = 1; off < SEG; off <<= 1) {
            float t = __shfl_up(incl, off, SEG);
            if (seg >= off) incl *= t;
        }
        float excl = __shfl_up(incl, 1, SEG);
        if (seg == 0) excl = 1.0f;

        float c0 = excl * F0, c1 = excl * F1, c2 = excl * F2;
        #pragma unroll
        for (int m = 1; m < SEG; m <<= 1) {
            c0 += __shfl_xor(c0, m, SEG);
            c1 += __shfl_xor(c1, m, SEG);
            c2 += __shfl_xor(c2, m, SEG);
            P  *= __shfl_xor(P, m, SEG);
        }

        float local_col = 0.f, local_sil = 0.f;
        if (seg == 0) {
            const float opac = 1.0f - P;
            local_sil = huber01(opac - tsil[pix]);
            const float* ti = timg + pix * 3;
            local_col = huber01(c0 - ti[0]) + huber01(c1 - ti[1]) + huber01(c2 - ti[2]);
        }

        #pragma unroll
        for (int m = 1; m < 64; m <<= 1) {
            local_col += __shfl_xor(local_col, m, 64);
            local_sil += __shfl_xor(local_sil, m, 64);
        }
        __shared__ float sc[4], ss[4];
        const int wave = tid >> 6;
        if ((tid & 63) == 0) { sc[wave] = local_col; ss[wave] = local_sil; }
        __syncthreads();
        if (tid == 0) {
            atomicAdd(&ws[0], sc[0] + sc[1] + sc[2] + sc[3]);
            atomicAdd(&ws[1], ss[0] + ss[1] + ss[2] + ss[3]);
        }
    } else {
        // ---------------- BEV loss ----------------
        const int t = (blockIdx.x - RENDER_BLOCKS) * 256 + tid; // [0, VH*VW)
        float m = dens[t];
        #pragma unroll
        for (int z = 1; z < VD; ++z)
            m = fmaxf(m, dens[z * (VH * VW) + t]);
        float v = fabsf(m);
        #pragma unroll
        for (int msk = 1; msk < 64; msk <<= 1)
            v += __shfl_xor(v, msk, 64);
        __shared__ float sb[4];
        const int wave = tid >> 6;
        if ((tid & 63) == 0) sb[wave] = v;
        __syncthreads();
        if (tid == 0)
            atomicAdd(&ws[2], sb[0] + sb[1] + sb[2] + sb[3]);
    }
}

__global__ void finalize_kernel(const float* __restrict__ ws, float* __restrict__ out)
{
    if (threadIdx.x == 0) {
        out[0] = ws[0] / (float)(N_CAM * PH * PW * 3); // color_err
        out[1] = ws[1] / (float)(N_CAM * PH * PW);     // sil_err
        out[2] = ws[2] / (float)(VH * VW);             // bev_err
    }
}

extern "C" void kernel_launch(void* const* d_in, const int* in_sizes, int n_in,
                              void* d_out, int out_size, void* d_ws, size_t ws_size,
                              hipStream_t stream) {
    const float* dens      = (const float*)d_in[0];
    const float* cols      = (const float*)d_in[1];
    const float* tsil      = (const float*)d_in[2];
    const float* timg      = (const float*)d_in[3];
    const float* focal     = (const float*)d_in[4];
    const float* principal = (const float*)d_in[5];
    const float* Rm        = (const float*)d_in[6];
    const float* Tv        = (const float*)d_in[7];
    float* ws  = (float*)d_ws;
    float* out = (float*)d_out;

    hipMemsetAsync(ws, 0, 3 * sizeof(float), stream); // ws is poisoned each call

    work_kernel<<<TOTAL_BLOCKS, 256, 0, stream>>>(
        dens, cols, tsil, timg, focal, principal, Rm, Tv, ws);
    finalize_kernel<<<1, 64, 0, stream>>>(ws, out);
}

// Round 4
// 87.713 us; speedup vs baseline: 1.8223x; 1.2465x over previous
//
#include <hip/hip_runtime.h>
#include <math.h>

// Problem constants (match reference)
#define N_CAM 2
#define PH 96
#define PW 144
#define NPTS 200
#define VD 32
#define VH 128
#define VW 384

constexpr float MIN_DEPTH = 1.0f;
constexpr float MAX_DEPTH = 4000.0f;
constexpr float EPS_T = 1e-10f;
constexpr float VOXEL = 2.5f;

#define SEG 8                       // lanes per ray
#define PIX_PER_BLOCK (256 / SEG)   // 32
#define TOTAL_PIX (N_CAM * PH * PW) // 27648
#define RENDER_BLOCKS (TOTAL_PIX / PIX_PER_BLOCK) // 864
#define BEV_BLOCKS ((VH * VW) / 256)              // 192
#define TOTAL_BLOCKS (RENDER_BLOCKS + BEV_BLOCKS) // 1056

// ws layout: 4 floats per block (3 partials + pad). Written unconditionally by
// every block -> no zero-init needed (ws is 0xAA-poisoned each call).
// Round 3 post-mortem: ~2900 same-address device atomicAdds cost ~35-40us of
// serialized cross-XCD service; per-block partial stores + tiny reduce instead.
// Round 2 post-mortem: per-block __threadfence() = L2 wb+inv on gfx950 -> 90us.

__device__ __forceinline__ float huber01(float diff) {
    // (sqrt(1 + diff^2/0.01) - 1) * 0.1 ; always >= 0 so |.| is a no-op
    float t = diff * 10.0f;
    return (sqrtf(fmaf(t, t, 1.0f)) - 1.0f) * 0.1f;
}

__global__ __launch_bounds__(256) void work_kernel(
    const float* __restrict__ dens,      // [VD*VH*VW]
    const float* __restrict__ cols,      // [3*VD*VH*VW] planar
    const float* __restrict__ tsil,      // [N_CAM*PH*PW]
    const float* __restrict__ timg,      // [N_CAM*PH*PW*3]
    const float* __restrict__ focal,     // [N_CAM*2]
    const float* __restrict__ principal, // [N_CAM*2]
    const float* __restrict__ Rm,        // [N_CAM*9]
    const float* __restrict__ Tv,        // [N_CAM*3]
    float* __restrict__ ws)              // [TOTAL_BLOCKS*4] partials
{
    const int tid = threadIdx.x;
    float p0 = 0.f, p1 = 0.f, p2 = 0.f; // block partials (col, sil, bev)

    if (blockIdx.x < RENDER_BLOCKS) {
        // ---------------- render + losses ----------------
        const int seg = tid & (SEG - 1);
        const int pix = blockIdx.x * PIX_PER_BLOCK + (tid >> 3);

        const int n   = pix / (PH * PW);
        const int rem = pix - n * (PH * PW);
        const int h   = rem / PW;
        const int w   = rem - h * PW;

        const float dx = ((float)w + 0.5f - principal[n * 2 + 0]) / focal[n * 2 + 0];
        const float dy = ((float)h + 0.5f - principal[n * 2 + 1]) / focal[n * 2 + 1];
        const float* R  = Rm + n * 9;
        const float* Tc = Tv + n * 3;
        const float dwx = R[0] * dx + R[1] * dy + R[2];
        const float dwy = R[3] * dx + R[4] * dy + R[5];
        const float dwz = R[6] * dx + R[7] * dy + R[8];
        const float ox = -(Tc[0] * R[0] + Tc[1] * R[1] + Tc[2] * R[2]);
        const float oy = -(Tc[0] * R[3] + Tc[1] * R[4] + Tc[2] * R[5]);
        const float oz = -(Tc[0] * R[6] + Tc[1] * R[7] + Tc[2] * R[8]);

        const float inv_vox = 1.0f / VOXEL;
        const float bx = (VW - 1) * 0.5f;
        const float by = (VH - 1) * 0.5f;
        const float bz = (VD - 1) * 0.5f;
        const float dstep = (MAX_DEPTH - MIN_DEPTH) / (float)(NPTS - 1);

        // Analytic ray-box clamp in grid space: g_axis(t) in (-1, DIM).
        // Outside samples contribute exactly d=0 -> A,P *= 1.0f exactly in fp32.
        float tn = MIN_DEPTH, tf = MAX_DEPTH;
        {
            const float o3[3] = {ox, oy, oz};
            const float d3[3] = {dwx, dwy, dwz};
            const float b3[3] = {bx, by, bz};
            const float m3[3] = {(float)VW, (float)VH, (float)VD};
            #pragma unroll
            for (int ax = 0; ax < 3; ++ax) {
                const float o = o3[ax], dw = d3[ax], b = b3[ax], dim = m3[ax];
                if (fabsf(dw) > 1e-12f) {
                    const float ta = ((-1.0f - b) * VOXEL - o) / dw;
                    const float tb = ((dim  - b) * VOXEL - o) / dw;
                    tn = fmaxf(tn, fminf(ta, tb));
                    tf = fminf(tf, fmaxf(ta, tb));
                } else {
                    const float g = o * inv_vox + b;
                    if (!(g > -1.0f && g < dim)) { tn = 1.0f; tf = 0.0f; }
                }
            }
        }
        int k0 = (int)ceilf((tn - MIN_DEPTH) / dstep) - 1;  // -1 margin
        int k1 = (int)floorf((tf - MIN_DEPTH) / dstep) + 2; // exclusive, +1 margin
        k0 = max(k0, 0);
        k1 = min(k1, NPTS);
        if (k1 < k0) k1 = k0;
        const int len = k1 - k0;
        const int L = (len + SEG - 1) / SEG; // contiguous chunk per lane
        const int s0 = k0 + seg * L;
        const int s1 = min(k1, s0 + L);

        float F0 = 0.f, F1 = 0.f, F2 = 0.f;
        float A = 1.0f, P = 1.0f;
        const int S = VD * VH * VW;

        for (int k = s0; k < s1; ++k) {
            const float depth = fmaf((float)k, dstep, MIN_DEPTH);
            const float gx = fmaf(fmaf(depth, dwx, ox), inv_vox, bx);
            const float gy = fmaf(fmaf(depth, dwy, oy), inv_vox, by);
            const float gz = fmaf(fmaf(depth, dwz, oz), inv_vox, bz);

            float d = 0.f, r = 0.f, g = 0.f, b = 0.f;
            if (gx > -1.f && gx < (float)VW &&
                gy > -1.f && gy < (float)VH &&
                gz > -1.f && gz < (float)VD) {
                const float x0f = floorf(gx), y0f = floorf(gy), z0f = floorf(gz);
                const float fx = gx - x0f, fy = gy - y0f, fz = gz - z0f;
                const int x0 = (int)x0f, y0 = (int)y0f, z0 = (int)z0f;
                #pragma unroll
                for (int c8 = 0; c8 < 8; ++c8) {
                    const int dxl = c8 & 1, dyl = (c8 >> 1) & 1, dzl = c8 >> 2;
                    const int xi = x0 + dxl, yi = y0 + dyl, zi = z0 + dzl;
                    if (xi < 0 || xi >= VW || yi < 0 || yi >= VH || zi < 0 || zi >= VD)
                        continue;
                    const float wt = (dxl ? fx : 1.f - fx) *
                                     (dyl ? fy : 1.f - fy) *
                                     (dzl ? fz : 1.f - fz);
                    const int flat = (zi * VH + yi) * VW + xi;
                    d = fmaf(dens[flat],         wt, d);
                    r = fmaf(cols[flat],         wt, r);
                    g = fmaf(cols[S + flat],     wt, g);
                    b = fmaf(cols[2 * S + flat], wt, b);
                }
            }
            const float wgt = d * A;
            F0 = fmaf(wgt, r, F0);
            F1 = fmaf(wgt, g, F1);
            F2 = fmaf(wgt, b, F2);
            A *= (1.0f + EPS_T - d);
            P *= (1.0f - d);
        }

        // Combine 8 contiguous segments (lanes) of this ray via shuffle scan.
        float incl = A;
        #pragma unroll
        for (int off = 1; off < SEG; off <<= 1) {
            float t = __shfl_up(incl, off, SEG);
            if (seg >= off) incl *= t;
        }
        float excl = __shfl_up(incl, 1, SEG);
        if (seg == 0) excl = 1.0f;

        float c0 = excl * F0, c1 = excl * F1, c2 = excl * F2;
        #pragma unroll
        for (int m = 1; m < SEG; m <<= 1) {
            c0 += __shfl_xor(c0, m, SEG);
            c1 += __shfl_xor(c1, m, SEG);
            c2 += __shfl_xor(c2, m, SEG);
            P  *= __shfl_xor(P, m, SEG);
        }

        float local_col = 0.f, local_sil = 0.f;
        if (seg == 0) {
            const float opac = 1.0f - P;
            local_sil = huber01(opac - tsil[pix]);
            const float* ti = timg + pix * 3;
            local_col = huber01(c0 - ti[0]) + huber01(c1 - ti[1]) + huber01(c2 - ti[2]);
        }

        #pragma unroll
        for (int m = 1; m < 64; m <<= 1) {
            local_col += __shfl_xor(local_col, m, 64);
            local_sil += __shfl_xor(local_sil, m, 64);
        }
        __shared__ float sc[4], ss[4];
        const int wave = tid >> 6;
        if ((tid & 63) == 0) { sc[wave] = local_col; ss[wave] = local_sil; }
        __syncthreads();
        p0 = sc[0] + sc[1] + sc[2] + sc[3];
        p1 = ss[0] + ss[1] + ss[2] + ss[3];
    } else {
        // ---------------- BEV loss ----------------
        const int t = (blockIdx.x - RENDER_BLOCKS) * 256 + tid; // [0, VH*VW)
        float m = dens[t];
        #pragma unroll
        for (int z = 1; z < VD; ++z)
            m = fmaxf(m, dens[z * (VH * VW) + t]);
        float v = fabsf(m);
        #pragma unroll
        for (int msk = 1; msk < 64; msk <<= 1)
            v += __shfl_xor(v, msk, 64);
        __shared__ float sb[4];
        const int wave = tid >> 6;
        if ((tid & 63) == 0) sb[wave] = v;
        __syncthreads();
        p2 = sb[0] + sb[1] + sb[2] + sb[3];
    }

    // One plain 3-float store per block to a distinct slot. NO atomics.
    if (tid == 0) {
        float* slot = ws + (size_t)blockIdx.x * 4;
        slot[0] = p0;
        slot[1] = p1;
        slot[2] = p2;
    }
}

__global__ __launch_bounds__(256) void finalize_kernel(
    const float* __restrict__ ws, float* __restrict__ out)
{
    const int tid = threadIdx.x;
    float s0 = 0.f, s1 = 0.f, s2 = 0.f;
    for (int i = tid; i < TOTAL_BLOCKS; i += 256) {
        const float* slot = ws + (size_t)i * 4;
        s0 += slot[0];
        s1 += slot[1];
        s2 += slot[2];
    }
    #pragma unroll
    for (int m = 1; m < 64; m <<= 1) {
        s0 += __shfl_xor(s0, m, 64);
        s1 += __shfl_xor(s1, m, 64);
        s2 += __shfl_xor(s2, m, 64);
    }
    __shared__ float a0[4], a1[4], a2[4];
    const int wave = tid >> 6;
    if ((tid & 63) == 0) { a0[wave] = s0; a1[wave] = s1; a2[wave] = s2; }
    __syncthreads();
    if (tid == 0) {
        const float csum = a0[0] + a0[1] + a0[2] + a0[3];
        const float ssum = a1[0] + a1[1] + a1[2] + a1[3];
        const float bsum = a2[0] + a2[1] + a2[2] + a2[3];
        out[0] = csum / (float)(N_CAM * PH * PW * 3); // color_err
        out[1] = ssum / (float)(N_CAM * PH * PW);     // sil_err
        out[2] = bsum / (float)(VH * VW);             // bev_err
    }
}

extern "C" void kernel_launch(void* const* d_in, const int* in_sizes, int n_in,
                              void* d_out, int out_size, void* d_ws, size_t ws_size,
                              hipStream_t stream) {
    const float* dens      = (const float*)d_in[0];
    const float* cols      = (const float*)d_in[1];
    const float* tsil      = (const float*)d_in[2];
    const float* timg      = (const float*)d_in[3];
    const float* focal     = (const float*)d_in[4];
    const float* principal = (const float*)d_in[5];
    const float* Rm        = (const float*)d_in[6];
    const float* Tv        = (const float*)d_in[7];
    float* ws  = (float*)d_ws;
    float* out = (float*)d_out;

    // No memset: every ws slot used is written unconditionally by work_kernel.
    work_kernel<<<TOTAL_BLOCKS, 256, 0, stream>>>(
        dens, cols, tsil, timg, focal, principal, Rm, Tv, ws);
    finalize_kernel<<<1, 256, 0, stream>>>(ws, out);
}